// Round 8
// baseline (14039.664 us; speedup 1.0000x reference)
//
#include <hip/hip_runtime.h>

typedef _Float16 half2_t __attribute__((ext_vector_type(2)));
typedef __bf16   bf16x8  __attribute__((ext_vector_type(8)));
typedef float    f32x4   __attribute__((ext_vector_type(4)));
typedef unsigned short u16x8 __attribute__((ext_vector_type(8)));
typedef unsigned int  uint32;
typedef unsigned long long uint64;

#define LSTM_N 32
#define LSTM_T 2048
#define LSTM_D 256
#define LSTM_H 256
#define NG 1024
#define CH 256                    // time-chunk length
#define NCH (LSTM_T / CH)         // 8 chunks
#define MCH (LSTM_N * CH)         // 8192 rows per chunk GEMM

// ---- workspace layout (bytes) ---- (~34.7 MB, proven safe R2-R7)
#define OFF_XG   ((size_t)0)
#define SZ_XG    ((size_t)MCH * NG * 4)             // 33,554,432 xg chunk f32
#define OFF_WIHB (OFF_XG + SZ_XG)
#define SZ_WIHB  ((size_t)NG * LSTM_D * 2)          // w_ih bf16
#define OFF_BIAS (OFF_WIHB + SZ_WIHB)
#define SZ_BIAS  ((size_t)4096)
#define OFF_WPK  (OFF_BIAS + SZ_BIAS)
#define SZ_WPK   ((size_t)2 * 32 * 512 * 16)        // 524,288 w_hh f16 pairs (per-WG layout)
#define OFF_CST  (OFF_WPK + SZ_WPK)
#define SZ_CST   ((size_t)LSTM_N * 256 * 4)         // c state f32
#define OFF_HST  (OFF_CST + SZ_CST)
#define SZ_HST   ((size_t)LSTM_N * 128 * 4)         // h state f16-pairs (u32)
#define OFF_HXD  (OFF_HST + SZ_HST)
#define SZ_HXD   ((size_t)LSTM_N * 2 * 2 * 64 * 4)  // 32,768 data slots (u32 pair, parity dbuf)
#define OFF_HXF  (OFF_HXD + SZ_HXD)
#define SZ_HXF   ((size_t)LSTM_N * 2 * 16 * 4)      // 4,096 flags (64B-padded)

#if defined(__has_builtin)
#if __has_builtin(__builtin_amdgcn_fdot2)
#define HAVE_FDOT2 1
#endif
#endif

// PROVEN datapath (R2/R3/R6, absmax 0.0078). The inline-asm v_dot2 variant is
// numerically WRONG on gfx950 (R5/R7 both failed with identical absmax) - banned.
__device__ __forceinline__ float fdot2(uint32 w, uint32 h, float acc) {
#ifdef HAVE_FDOT2
  return __builtin_amdgcn_fdot2(__builtin_bit_cast(half2_t, w),
                                __builtin_bit_cast(half2_t, h), acc, false);
#else
  half2_t wv = __builtin_bit_cast(half2_t, w);
  half2_t hv = __builtin_bit_cast(half2_t, h);
  float r = fmaf((float)wv.x, (float)hv.x, acc);
  return fmaf((float)wv.y, (float)hv.y, r);
#endif
}

__device__ __forceinline__ float sigm(float x) { return 1.f / (1.f + __expf(-x)); }
__device__ __forceinline__ float tanh_fast(float x) { return 2.f / (1.f + __expf(-2.f * x)) - 1.f; }

__device__ __forceinline__ unsigned short f2bf(float f) {
  uint32 u = __builtin_bit_cast(uint32, f);
  uint32 r = (u + 0x7FFFu + ((u >> 16) & 1u)) >> 16;
  return (unsigned short)r;
}

// reduce-scatter over 8 kappa-lanes: lane kap ends with full sum of a[kap].
// Compile-time register indices only (rule #20). Proven R2/R3/R6.
__device__ __forceinline__ float bfly8(const float a[8], int kap) {
  float k0[4], g0[4];
  const bool b4 = (kap & 4) != 0;
#pragma unroll
  for (int v = 0; v < 4; ++v) {
    k0[v] = b4 ? a[v + 4] : a[v];
    g0[v] = b4 ? a[v] : a[v + 4];
  }
#pragma unroll
  for (int v = 0; v < 4; ++v) k0[v] += __shfl_xor(g0[v], 4, 64);
  float k1[2], g1[2];
  const bool b2 = (kap & 2) != 0;
#pragma unroll
  for (int v = 0; v < 2; ++v) {
    k1[v] = b2 ? k0[v + 2] : k0[v];
    g1[v] = b2 ? k0[v] : k0[v + 2];
  }
#pragma unroll
  for (int v = 0; v < 2; ++v) k1[v] += __shfl_xor(g1[v], 2, 64);
  const bool b1 = (kap & 1) != 0;
  float k2 = b1 ? k1[1] : k1[0];
  float g2 = b1 ? k1[0] : k1[1];
  return k2 + __shfl_xor(g2, 1, 64);
}

// ---------------- kernels (cvt/bias/wpack/gemm = R3/R6 verbatim) ----------------

__global__ void cvt_bf16_k(const float* __restrict__ src, unsigned short* __restrict__ dst, int n) {
  int i = blockIdx.x * blockDim.x + threadIdx.x;
  if (4 * i + 3 < n) {
    float4 v = ((const float4*)src)[i];
    ushort4 o;
    o.x = f2bf(v.x); o.y = f2bf(v.y); o.z = f2bf(v.z); o.w = f2bf(v.w);
    ((ushort4*)dst)[i] = o;
  }
}

__global__ void bias_sum_k(const float* __restrict__ bih, const float* __restrict__ bhh,
                           float* __restrict__ bias) {
  int g = blockIdx.x * blockDim.x + threadIdx.x;
  if (g < NG) bias[g] = bih[g] + bhh[g];
}

// Pack w_hh f32[1024][256] -> per-(WG p, thread t) f16-pair reg images. [R3/R6 verbatim]
__global__ void wpack_k(const float* __restrict__ whh, uint32* __restrict__ wpk) {
  int e = blockIdx.x * blockDim.x + threadIdx.x;  // < 131072
  int p = e >> 16;
  int rem = e & 0xFFFF;
  int i = rem >> 9;        // 0..127
  int t = rem & 511;
  int rho = i >> 4, j = i & 15;
  int kap = t & 7, rg = t >> 3;
  int lr = 8 * rg + rho;
  int q = lr >> 7, u = lr & 127;
  int r = q * 256 + 128 * p + u;
  int k = (j < 8) ? (128 * p + 16 * kap + 2 * j)
                  : (128 * (1 - p) + 16 * kap + 2 * (j - 8));
  half2_t h;
  h.x = (_Float16)whh[r * 256 + k];
  h.y = (_Float16)whh[r * 256 + k + 1];
  wpk[((p * 32 + (i >> 2)) * 512 + t) * 4 + (i & 3)] = __builtin_bit_cast(uint32, h);
}

// init carried state + pre-post parity-0 exchange data + zero flags (replay-safe)
__global__ void state_init_k(const float* __restrict__ state, float* __restrict__ cst,
                             uint32* __restrict__ hst, uint32* __restrict__ hxd,
                             uint32* __restrict__ hxf) {
  int i = blockIdx.x * blockDim.x + threadIdx.x;  // < 8192
  int n = i >> 8, j = i & 255;
  cst[i] = state[n * 512 + 256 + j];
  if ((j & 1) == 0) {
    half2_t h2;
    h2.x = (_Float16)state[n * 512 + j];
    h2.y = (_Float16)state[n * 512 + j + 1];
    hst[(n << 7) + (j >> 1)] = __builtin_bit_cast(uint32, h2);
  }
  if (j < 128) {  // parity-0 data slots: pair (128p+2s, +1) of half p
    int p = j >> 6, s = j & 63;
    half2_t h2;
    h2.x = (_Float16)state[n * 512 + 128 * p + 2 * s];
    h2.y = (_Float16)state[n * 512 + 128 * p + 2 * s + 1];
    hxd[(n * 2 + p) * 128 + s] = __builtin_bit_cast(uint32, h2);
  } else if (j < 130) {
    hxf[(n * 2 + (j - 128)) * 16] = 0u;  // flags
  }
}

// xg[8192][1024] = x(chunk rows, cvt bf16 inline) @ w_ih_bf16^T + bias  [R2/R3 verbatim]
__global__ __launch_bounds__(256) void gemm_xg(const float* __restrict__ x,
                                               const unsigned short* __restrict__ wb,
                                               const float* __restrict__ bias,
                                               float* __restrict__ xg, int ch) {
  __shared__ unsigned short As[128 * 40];  // 80B rows (stride = 5*16B, odd*16)
  __shared__ unsigned short Bs[128 * 40];
  const int tid = threadIdx.x;
  const int m0 = blockIdx.y * 128;
  const int g0 = blockIdx.x * 128;
  const int w = tid >> 6;
  const int lane = tid & 63;
  const int wm = (w >> 1) * 64, wn = (w & 1) * 64;
  const int row_l = tid >> 2;  // 0..63
  const int q = tid & 3;
  const int lr = lane & 15, kg = lane >> 4;

  size_t grow[2];
#pragma unroll
  for (int r = 0; r < 2; ++r) {
    int gm = m0 + row_l + 64 * r;
    grow[r] = (size_t)(gm >> 8) * LSTM_T + (size_t)ch * CH + (gm & 255);
  }

  f32x4 acc[4][4];
#pragma unroll
  for (int i = 0; i < 4; ++i)
#pragma unroll
    for (int j = 0; j < 4; ++j) acc[i][j] = (f32x4){0.f, 0.f, 0.f, 0.f};

  for (int kt = 0; kt < 8; ++kt) {
#pragma unroll
    for (int r = 0; r < 2; ++r) {
      int row = row_l + 64 * r;
      const float* ap = x + grow[r] * 256 + kt * 32 + q * 8;
      float4 v0 = *(const float4*)ap;
      float4 v1 = *(const float4*)(ap + 4);
      u16x8 o;
      o[0] = f2bf(v0.x); o[1] = f2bf(v0.y); o[2] = f2bf(v0.z); o[3] = f2bf(v0.w);
      o[4] = f2bf(v1.x); o[5] = f2bf(v1.y); o[6] = f2bf(v1.z); o[7] = f2bf(v1.w);
      *(uint4*)((char*)As + row * 80 + q * 16) = __builtin_bit_cast(uint4, o);
      uint4 bv = *(const uint4*)(wb + (size_t)(g0 + row) * 256 + kt * 32 + q * 8);
      *(uint4*)((char*)Bs + row * 80 + q * 16) = bv;
    }
    __syncthreads();
    bf16x8 af[4], bfr[4];
#pragma unroll
    for (int i = 0; i < 4; ++i)
      af[i] = __builtin_bit_cast(bf16x8, *(const uint4*)((char*)As + (wm + 16 * i + lr) * 80 + kg * 16));
#pragma unroll
    for (int j = 0; j < 4; ++j)
      bfr[j] = __builtin_bit_cast(bf16x8, *(const uint4*)((char*)Bs + (wn + 16 * j + lr) * 80 + kg * 16));
#pragma unroll
    for (int i = 0; i < 4; ++i)
#pragma unroll
      for (int j = 0; j < 4; ++j)
        acc[i][j] = __builtin_amdgcn_mfma_f32_16x16x32_bf16(af[i], bfr[j], acc[i][j], 0, 0, 0);
    __syncthreads();
  }
#pragma unroll
  for (int j = 0; j < 4; ++j) {
    int gc = g0 + wn + 16 * j + lr;
    float bj = bias[gc];
#pragma unroll
    for (int i = 0; i < 4; ++i) {
#pragma unroll
      for (int r = 0; r < 4; ++r) {
        int m = m0 + wm + 16 * i + kg * 4 + r;
        xg[(size_t)m * NG + gc] = acc[i][j][r] + bj;
      }
    }
  }
}

// Recurrent scan: R6-proven datapath (builtin fdot2) + flag-gated exchange
// (acquire spin + 8 single-shot loads), own-dots-before-spin overlap, 2
// barriers/step, LDS-staged output flushed every 16 steps.
// Thread t: kap=t&7 (k-slice), rg=t>>3 (rows 8rg..8rg+7); finalizes row lr=t:
// gate q=t>>7, unit u=t&127, row R=q*256+128p+u.
__global__ __launch_bounds__(512, 1) void lstm_scan(const float* __restrict__ xg,
                                                    const uint4* __restrict__ wpk4,
                                                    float* __restrict__ cst,
                                                    uint32* __restrict__ hst,
                                                    uint32* __restrict__ hxd,
                                                    uint32* __restrict__ hxf,
                                                    float* __restrict__ out, int ch) {
  __shared__ float actb[512];
  __shared__ uint32 hown[2][64];      // own-half h f16-pairs, parity per step
  __shared__ float ostage[16][128];   // h staging, flushed every 16 steps

  const int b = blockIdx.x;
  const int n = b & 31;
  const int p = b >> 5;
  const int t = threadIdx.x;
  const int kap = t & 7;
  const int q = t >> 7;                 // wave-uniform gate: 0=i 1=f 2=g 3=o
  const int u = t & 127;
  const int R = q * 256 + 128 * p + u;  // finalized gate row

  // weights -> 128 regs (compiler may AGPR-split; builtin fdot2 pays the copy)
  uint32 wr[128];
#pragma unroll
  for (int ig = 0; ig < 32; ++ig) {
    uint4 v = wpk4[(p * 32 + ig) * 512 + t];
    wr[4 * ig + 0] = v.x; wr[4 * ig + 1] = v.y; wr[4 * ig + 2] = v.z; wr[4 * ig + 3] = v.w;
  }
  float c = 0.f;
  if (t < 128) c = cst[n * 256 + 128 * p + t];
  if (t < 64) hown[0][t] = hst[n * 128 + 64 * p + t];
  __syncthreads();

  const float* xgn = xg + (size_t)n * CH * NG;
  float* outb = out + ((size_t)n * LSTM_T + (size_t)ch * CH) * LSTM_H;
  uint32* hxd_own  = hxd + (size_t)(n * 2 + p) * 128;
  uint32* hxd_peer = hxd + (size_t)(n * 2 + (1 - p)) * 128;
  uint32* hxf_own  = hxf + (size_t)(n * 2 + p) * 16;
  uint32* hxf_peer = hxf + (size_t)(n * 2 + (1 - p)) * 16;
  const int gsbase = ch * CH;

  float xcur = xgn[R];

  for (int tt = 0; tt < CH; ++tt) {
    const uint32 gs = (uint32)(gsbase + tt);
    // xg prefetch for next step (hidden under dots)
    float xnext = (tt < CH - 1) ? xgn[(size_t)(tt + 1) * NG + R] : 0.f;
    // own h-slice (broadcast LDS reads, parity buffer)
    uint32 hro[8];
    *(uint4*)&hro[0] = *(const uint4*)&hown[tt & 1][8 * kap];
    *(uint4*)&hro[4] = *(const uint4*)&hown[tt & 1][8 * kap + 4];
    // own-half partial dots FIRST (overlaps peer's posting latency)
    float acc[8];
#pragma unroll
    for (int j = 0; j < 8; ++j) {
      float a = 0.f;
#pragma unroll
      for (int m = 0; m < 8; ++m) a = fdot2(wr[j * 16 + m], hro[m], a);
      acc[j] = a;
    }
    // spin on peer flag (monotone step counter; acquire orders the data loads)
    uint32 fv;
    do {
      fv = __hip_atomic_load(hxf_peer, __ATOMIC_ACQUIRE, __HIP_MEMORY_SCOPE_AGENT);
    } while ((int)(fv - gs) < 0);
    __builtin_amdgcn_sched_barrier(0);
    // single-shot peer data loads (posted before the flag -> guaranteed fresh)
    uint32 hrp[8];
    {
      uint32* sp = &hxd_peer[(size_t)(tt & 1) * 64 + 8 * kap];
#pragma unroll
      for (int ss = 0; ss < 8; ++ss)
        hrp[ss] = __hip_atomic_load(&sp[ss], __ATOMIC_RELAXED, __HIP_MEMORY_SCOPE_AGENT);
    }
    // peer-half partial dots
#pragma unroll
    for (int j = 0; j < 8; ++j) {
      float a = acc[j];
#pragma unroll
      for (int m = 0; m < 8; ++m) a = fdot2(wr[j * 16 + 8 + m], hrp[m], a);
      acc[j] = a;
    }
    float s = bfly8(acc, kap);
    float pre = s + xcur;
    xcur = xnext;
    float a0 = (q == 2) ? tanh_fast(pre) : sigm(pre);
    actb[t] = a0;
    __syncthreads();                        // BAR-A: gates ready
    if (t < 128) {                          // cell update: unit t of own half
      float gi = actb[t];
      float gf = actb[128 + t];
      float gg = actb[256 + t];
      float go = actb[384 + t];
      c = gf * c + gi * gg;
      float h = go * tanh_fast(c);
      _Float16 hf = (_Float16)h;
      unsigned short hu = __builtin_bit_cast(unsigned short, hf);
      ((unsigned short*)&hown[(tt + 1) & 1][0])[t] = hu;   // next-step own half
      ostage[tt & 15][t] = h;                              // staged output
      uint32 hz = (uint32)hu;
      uint32 hn = (uint32)__shfl_xor((int)hz, 1, 64);      // partner unit t^1
      if ((t & 1) == 0) {  // post pair (t, t+1) for peer's next step (parity dbuf)
        __hip_atomic_store(&hxd_own[(size_t)((tt + 1) & 1) * 64 + (t >> 1)],
                           hz | (hn << 16), __ATOMIC_RELAXED, __HIP_MEMORY_SCOPE_AGENT);
      }
      if (ch == NCH - 1 && tt == CH - 1) {
        float* os = out + (size_t)LSTM_N * LSTM_T * LSTM_H + n * 512;
        os[128 * p + t] = h;
        os[256 + 128 * p + t] = c;
      }
    }
    __syncthreads();   // BAR-B: hown/ostage visible; data posts drained (vmcnt)
    if (t == 0)        // publish: "data for step gs+1 is posted" (release)
      __hip_atomic_store(hxf_own, gs + 1, __ATOMIC_RELEASE, __HIP_MEMORY_SCOPE_AGENT);
    if ((tt & 15) == 15) {  // flush 16 staged steps, coalesced
      int sl = t >> 5, q4 = t & 31;
      float4 v = *(const float4*)&ostage[sl][4 * q4];
      *(float4*)&outb[(size_t)(tt - 15 + sl) * LSTM_H + 128 * p + 4 * q4] = v;
    }
  }
  // persist carried state (CH even -> final h landed in hown[0])
  if (t < 128) cst[n * 256 + 128 * p + t] = c;
  if (t < 64) hst[n * 128 + 64 * p + t] = hown[0][t];
}

extern "C" void kernel_launch(void* const* d_in, const int* in_sizes, int n_in,
                              void* d_out, int out_size, void* d_ws, size_t ws_size,
                              hipStream_t stream) {
  const float* x   = (const float*)d_in[0];
  const float* st  = (const float*)d_in[1];
  const float* wih = (const float*)d_in[2];
  const float* whh = (const float*)d_in[3];
  const float* bih = (const float*)d_in[4];
  const float* bhh = (const float*)d_in[5];
  float* out = (float*)d_out;
  char* ws = (char*)d_ws;

  float* xg = (float*)(ws + OFF_XG);
  unsigned short* wihb = (unsigned short*)(ws + OFF_WIHB);
  float* bias = (float*)(ws + OFF_BIAS);
  uint32* wpk = (uint32*)(ws + OFF_WPK);
  float* cst = (float*)(ws + OFF_CST);
  uint32* hst = (uint32*)(ws + OFF_HST);
  uint32* hxd = (uint32*)(ws + OFF_HXD);
  uint32* hxf = (uint32*)(ws + OFF_HXF);

  cvt_bf16_k<<<(NG * LSTM_D / 4 + 255) / 256, 256, 0, stream>>>(wih, wihb, NG * LSTM_D);
  bias_sum_k<<<4, 256, 0, stream>>>(bih, bhh, bias);
  wpack_k<<<512, 256, 0, stream>>>(whh, wpk);
  state_init_k<<<32, 256, 0, stream>>>(st, cst, hst, hxd, hxf);

  for (int ch = 0; ch < NCH; ++ch) {
    gemm_xg<<<dim3(NG / 128, MCH / 128), 256, 0, stream>>>(x, wihb, bias, xg, ch);
    lstm_scan<<<64, 512, 0, stream>>>(xg, (const uint4*)wpk, cst, hst, hxd, hxf, out, ch);
  }
}

// Round 9
// 2978.355 us; speedup vs baseline: 4.7139x; 4.7139x over previous
//
#include <hip/hip_runtime.h>

typedef _Float16 half2_t __attribute__((ext_vector_type(2)));
typedef __bf16   bf16x8  __attribute__((ext_vector_type(8)));
typedef float    f32x4   __attribute__((ext_vector_type(4)));
typedef unsigned short u16x8 __attribute__((ext_vector_type(8)));
typedef unsigned int  uint32;
typedef unsigned long long uint64;

#define LSTM_N 32
#define LSTM_T 2048
#define LSTM_D 256
#define LSTM_H 256
#define NG 1024
#define CH 256                    // time-chunk length
#define NCH (LSTM_T / CH)         // 8 chunks
#define MCH (LSTM_N * CH)         // 8192 rows per chunk GEMM

// ---- workspace layout (bytes) ---- (~34.7 MB, proven safe R2-R8)
#define OFF_XG   ((size_t)0)
#define SZ_XG    ((size_t)MCH * NG * 4)             // 33,554,432 xg chunk f32
#define OFF_WIHB (OFF_XG + SZ_XG)
#define SZ_WIHB  ((size_t)NG * LSTM_D * 2)          // w_ih bf16
#define OFF_BIAS (OFF_WIHB + SZ_WIHB)
#define SZ_BIAS  ((size_t)4096)
#define OFF_WPK  (OFF_BIAS + SZ_BIAS)
#define SZ_WPK   ((size_t)2 * 512 * 128 * 4)        // 524,288 w_hh f16 pairs (R5 layout)
#define OFF_CST  (OFF_WPK + SZ_WPK)
#define SZ_CST   ((size_t)LSTM_N * 256 * 4)         // c state f32
#define OFF_HST  (OFF_CST + SZ_CST)
#define SZ_HST   ((size_t)LSTM_N * 128 * 4)         // h state f16-pairs (u32)
#define OFF_HX   (OFF_HST + SZ_HST)
#define SZ_HX    ((size_t)LSTM_N * 2 * 2 * 64 * 8)  // 65,536 tagged-u64 exchange slots

#if defined(__has_builtin)
#if __has_builtin(__builtin_amdgcn_fdot2)
#define HAVE_FDOT2 1
#endif
#endif

// PROVEN datapath (R2/R3/R6/R8, absmax 0.0078). Inline-asm v_dot2 is numerically
// WRONG on gfx950 (R5/R7 failed identically at 0.0839) - permanently banned.
__device__ __forceinline__ float fdot2(uint32 w, uint32 h, float acc) {
#ifdef HAVE_FDOT2
  return __builtin_amdgcn_fdot2(__builtin_bit_cast(half2_t, w),
                                __builtin_bit_cast(half2_t, h), acc, false);
#else
  half2_t wv = __builtin_bit_cast(half2_t, w);
  half2_t hv = __builtin_bit_cast(half2_t, h);
  float r = fmaf((float)wv.x, (float)hv.x, acc);
  return fmaf((float)wv.y, (float)hv.y, r);
#endif
}

__device__ __forceinline__ float sigm(float x) { return 1.f / (1.f + __expf(-x)); }
__device__ __forceinline__ float tanh_fast(float x) { return 2.f / (1.f + __expf(-2.f * x)) - 1.f; }

__device__ __forceinline__ unsigned short f2bf(float f) {
  uint32 u = __builtin_bit_cast(uint32, f);
  uint32 r = (u + 0x7FFFu + ((u >> 16) & 1u)) >> 16;
  return (unsigned short)r;
}

// reduce-scatter over 8 kappa-lanes (masks 4/2/1 = bits 0-2 -> in-wave).
// Compile-time register indices only (rule #20). Proven R2/R3/R6/R8.
__device__ __forceinline__ float bfly8(const float a[8], int kap) {
  float k0[4], g0[4];
  const bool b4 = (kap & 4) != 0;
#pragma unroll
  for (int v = 0; v < 4; ++v) {
    k0[v] = b4 ? a[v + 4] : a[v];
    g0[v] = b4 ? a[v] : a[v + 4];
  }
#pragma unroll
  for (int v = 0; v < 4; ++v) k0[v] += __shfl_xor(g0[v], 4, 64);
  float k1[2], g1[2];
  const bool b2 = (kap & 2) != 0;
#pragma unroll
  for (int v = 0; v < 2; ++v) {
    k1[v] = b2 ? k0[v + 2] : k0[v];
    g1[v] = b2 ? k0[v] : k0[v + 2];
  }
#pragma unroll
  for (int v = 0; v < 2; ++v) k1[v] += __shfl_xor(g1[v], 2, 64);
  const bool b1 = (kap & 1) != 0;
  float k2 = b1 ? k1[1] : k1[0];
  float g2 = b1 ? k1[0] : k1[1];
  return k2 + __shfl_xor(g2, 1, 64);
}

// ---------------- kernels ----------------

__global__ void cvt_bf16_k(const float* __restrict__ src, unsigned short* __restrict__ dst, int n) {
  int i = blockIdx.x * blockDim.x + threadIdx.x;
  if (4 * i + 3 < n) {
    float4 v = ((const float4*)src)[i];
    ushort4 o;
    o.x = f2bf(v.x); o.y = f2bf(v.y); o.z = f2bf(v.z); o.w = f2bf(v.w);
    ((ushort4*)dst)[i] = o;
  }
}

__global__ void bias_sum_k(const float* __restrict__ bih, const float* __restrict__ bhh,
                           float* __restrict__ bias) {
  int g = blockIdx.x * blockDim.x + threadIdx.x;
  if (g < NG) bias[g] = bih[g] + bhh[g];
}

// Pack w_hh f32[1024][256] -> f16-pair images for scan WG p, thread t. [R5 layout]
// Thread t: w=t>>6, l=t&63, q=l>>4, b3=(l>>3)&1, kap=l&7.
// wr[j*16+m]: row = q*256+128p+16w+8b3+j (j=0..7);
//             k = m<8 ? 128p+16kap+2m : 128(1-p)+16kap+2(m-8).
__global__ void wpack_k(const float* __restrict__ whh, uint32* __restrict__ wpk) {
  int e = blockIdx.x * blockDim.x + threadIdx.x;  // < 131072
  int p = e >> 16;
  int i128 = (e >> 9) & 127;
  int t = e & 511;
  int j = i128 >> 4, m = i128 & 15;
  int w = t >> 6, l = t & 63;
  int q = l >> 4, b3 = (l >> 3) & 1, kap = l & 7;
  int row = q * 256 + 128 * p + 16 * w + 8 * b3 + j;
  int k = (m < 8) ? (128 * p + 16 * kap + 2 * m)
                  : (128 * (1 - p) + 16 * kap + 2 * (m - 8));
  half2_t h;
  h.x = (_Float16)whh[row * 256 + k];
  h.y = (_Float16)whh[row * 256 + k + 1];
  wpk[((i128 >> 2) * 1024 + p * 512 + t) * 4 + (i128 & 3)] = __builtin_bit_cast(uint32, h);
}

// init carried state + zero exchange tags (every launch -> replay-safe) [R6 verbatim]
__global__ void state_init_k(const float* __restrict__ state, float* __restrict__ cst,
                             uint32* __restrict__ hst, uint64* __restrict__ hx) {
  int i = blockIdx.x * blockDim.x + threadIdx.x;  // < 8192
  int n = i >> 8, j = i & 255;
  cst[i] = state[n * 512 + 256 + j];
  if ((j & 1) == 0) {
    half2_t h2;
    h2.x = (_Float16)state[n * 512 + j];
    h2.y = (_Float16)state[n * 512 + j + 1];
    hst[(n << 7) + (j >> 1)] = __builtin_bit_cast(uint32, h2);
  }
  hx[i] = 0ull;
}

// xg[8192][1024] = x(chunk rows, cvt bf16 inline) @ w_ih_bf16^T + bias  [R2/R3 verbatim]
__global__ __launch_bounds__(256) void gemm_xg(const float* __restrict__ x,
                                               const unsigned short* __restrict__ wb,
                                               const float* __restrict__ bias,
                                               float* __restrict__ xg, int ch) {
  __shared__ unsigned short As[128 * 40];  // 80B rows (stride = 5*16B, odd*16)
  __shared__ unsigned short Bs[128 * 40];
  const int tid = threadIdx.x;
  const int m0 = blockIdx.y * 128;
  const int g0 = blockIdx.x * 128;
  const int w = tid >> 6;
  const int lane = tid & 63;
  const int wm = (w >> 1) * 64, wn = (w & 1) * 64;
  const int row_l = tid >> 2;  // 0..63
  const int q = tid & 3;
  const int lr = lane & 15, kg = lane >> 4;

  size_t grow[2];
#pragma unroll
  for (int r = 0; r < 2; ++r) {
    int gm = m0 + row_l + 64 * r;
    grow[r] = (size_t)(gm >> 8) * LSTM_T + (size_t)ch * CH + (gm & 255);
  }

  f32x4 acc[4][4];
#pragma unroll
  for (int i = 0; i < 4; ++i)
#pragma unroll
    for (int j = 0; j < 4; ++j) acc[i][j] = (f32x4){0.f, 0.f, 0.f, 0.f};

  for (int kt = 0; kt < 8; ++kt) {
#pragma unroll
    for (int r = 0; r < 2; ++r) {
      int row = row_l + 64 * r;
      const float* ap = x + grow[r] * 256 + kt * 32 + q * 8;
      float4 v0 = *(const float4*)ap;
      float4 v1 = *(const float4*)(ap + 4);
      u16x8 o;
      o[0] = f2bf(v0.x); o[1] = f2bf(v0.y); o[2] = f2bf(v0.z); o[3] = f2bf(v0.w);
      o[4] = f2bf(v1.x); o[5] = f2bf(v1.y); o[6] = f2bf(v1.z); o[7] = f2bf(v1.w);
      *(uint4*)((char*)As + row * 80 + q * 16) = __builtin_bit_cast(uint4, o);
      uint4 bv = *(const uint4*)(wb + (size_t)(g0 + row) * 256 + kt * 32 + q * 8);
      *(uint4*)((char*)Bs + row * 80 + q * 16) = bv;
    }
    __syncthreads();
    bf16x8 af[4], bfr[4];
#pragma unroll
    for (int i = 0; i < 4; ++i)
      af[i] = __builtin_bit_cast(bf16x8, *(const uint4*)((char*)As + (wm + 16 * i + lr) * 80 + kg * 16));
#pragma unroll
    for (int j = 0; j < 4; ++j)
      bfr[j] = __builtin_bit_cast(bf16x8, *(const uint4*)((char*)Bs + (wn + 16 * j + lr) * 80 + kg * 16));
#pragma unroll
    for (int i = 0; i < 4; ++i)
#pragma unroll
      for (int j = 0; j < 4; ++j)
        acc[i][j] = __builtin_amdgcn_mfma_f32_16x16x32_bf16(af[i], bfr[j], acc[i][j], 0, 0, 0);
    __syncthreads();
  }
#pragma unroll
  for (int j = 0; j < 4; ++j) {
    int gc = g0 + wn + 16 * j + lr;
    float bj = bias[gc];
#pragma unroll
    for (int i = 0; i < 4; ++i) {
#pragma unroll
      for (int r = 0; r < 4; ++r) {
        int m = m0 + wm + 16 * i + kg * 4 + r;
        xg[(size_t)m * NG + gc] = acc[i][j][r] + bj;
      }
    }
  }
}

// Recurrent scan: 64 WGs (n=b&31, p=b>>5; pair (b,b+32) same XCD round-robin).
// R5 lane mapping + builtin fdot2 + R3-proven tagged-u64 exchange.
// Lane (w=t>>6, l=t&63): q=l>>4 (gate), u=16w+(l&15) (unit in half), kap=l&7.
// Per step: own dots (all) | 64 pollers spin 1 slot each -> LDS; bar1; peer
// dots; bfly8; 1 exp; 3 shfl gate-gather; cell (all lanes, redundant x4);
// q0 lanes: hown parity write + ostage + post; bar2. 2 barriers/step.
__global__ __launch_bounds__(512, 1) void lstm_scan(const float* __restrict__ xg,
                                                    const uint4* __restrict__ wpk4,
                                                    float* __restrict__ cst,
                                                    uint32* __restrict__ hst,
                                                    uint64* __restrict__ hx,
                                                    float* __restrict__ out, int ch) {
  __shared__ uint32 hown[2][64];      // own-half h f16-pairs, parity per step
  __shared__ uint32 hpeer[64];        // peer-half deposit (single buffer, see proof)
  __shared__ float ostage[16][128];   // h staging, flushed every 16 steps

  const int b = blockIdx.x;
  const int n = b & 31;
  const int p = b >> 5;
  const int t = threadIdx.x;
  const int w = t >> 6, l = t & 63;
  const int q = l >> 4, kap = l & 7;
  const int u = 16 * w + (l & 15);      // unit within half
  const int R = q * 256 + 128 * p + u;  // finalized gate row

  // weights -> 128 regs (compiler may AGPR-split; builtin fdot2 pays the copy)
  uint32 wr[128];
#pragma unroll
  for (int ig = 0; ig < 32; ++ig) {
    uint4 v = wpk4[ig * 1024 + p * 512 + t];
    wr[4 * ig + 0] = v.x; wr[4 * ig + 1] = v.y; wr[4 * ig + 2] = v.z; wr[4 * ig + 3] = v.w;
  }
  float c = cst[n * 256 + 128 * p + u];   // 4-way redundant (broadcast load)
  if (t < 64) {
    hown[0][t] = hst[n * 128 + 64 * p + t];
    hpeer[t]   = hst[n * 128 + 64 * (1 - p) + t];  // step-0 peer half
  }
  __syncthreads();

  const float* xgn = xg + (size_t)n * CH * NG;
  float* outb = out + ((size_t)n * LSTM_T + (size_t)ch * CH) * LSTM_H;
  uint64* hx_own  = hx + (size_t)(n * 2 + p) * 128;
  uint64* hx_peer = hx + (size_t)(n * 2 + (1 - p)) * 128;
  const int gsbase = ch * CH;

  float xcur = xgn[R];

  for (int tt = 0; tt < CH; ++tt) {
    const uint32 gs = (uint32)(gsbase + tt);
    // xg prefetch for next step (hidden under dots)
    float xnext = (tt < CH - 1) ? xgn[(size_t)(tt + 1) * NG + R] : 0.f;
    // own h-slice (broadcast LDS reads, parity buffer)
    uint32 hro[8];
    *(uint4*)&hro[0] = *(const uint4*)&hown[tt & 1][8 * kap];
    *(uint4*)&hro[4] = *(const uint4*)&hown[tt & 1][8 * kap + 4];
    // own-half partial dots FIRST (8 rows x 8 pairs) - overlaps peer posting
    float acc[8];
#pragma unroll
    for (int j = 0; j < 8; ++j) {
      float a = 0.f;
#pragma unroll
      for (int m = 0; m < 8; ++m) a = fdot2(wr[j * 16 + m], hro[m], a);
      acc[j] = a;
    }
    // designated pollers: 1 tagged slot each (R3-proven protocol, relaxed)
    if (tt > 0 && t < 64) {
      uint64 v;
      do {
        v = __hip_atomic_load(&hx_peer[(size_t)(tt & 1) * 64 + t],
                              __ATOMIC_RELAXED, __HIP_MEMORY_SCOPE_AGENT);
      } while ((uint32)(v >> 32) != gs);
      hpeer[t] = (uint32)v;
    }
    __syncthreads();                    // BAR-1: peer half deposited
    // peer h-slice + peer-half partial dots
    uint32 hrp[8];
    *(uint4*)&hrp[0] = *(const uint4*)&hpeer[8 * kap];
    *(uint4*)&hrp[4] = *(const uint4*)&hpeer[8 * kap + 4];
#pragma unroll
    for (int j = 0; j < 8; ++j) {
      float a = acc[j];
#pragma unroll
      for (int m = 0; m < 8; ++m) a = fdot2(wr[j * 16 + 8 + m], hrp[m], a);
      acc[j] = a;
    }
    float s = bfly8(acc, kap);          // lane owns row R (rho = kap)
    float pre = s + xcur;
    xcur = xnext;
    // one exp per lane; q==2 uses tanh via 2*sigm(2x)-1 (exact doubling)
    float z = (q == 2) ? (2.f * pre) : pre;
    float sg = 1.f / (1.f + __expf(-z));
    float a_own = (q == 2) ? (2.f * sg - 1.f) : sg;
    // gather 4 gates of unit u (lanes l, l^16, l^32, l^48) - verified table
    float a1 = __shfl_xor(a_own, 16, 64);
    float a2 = __shfl_xor(a_own, 32, 64);
    float a3 = __shfl_xor(a1, 32, 64);
    float gi = (q == 0) ? a_own : ((q == 1) ? a1 : ((q == 2) ? a2 : a3));
    float gf = (q == 1) ? a_own : ((q == 0) ? a1 : ((q == 3) ? a2 : a3));
    float gg = (q == 2) ? a_own : ((q == 3) ? a1 : ((q == 0) ? a2 : a3));
    float go = (q == 3) ? a_own : ((q == 2) ? a1 : ((q == 1) ? a2 : a3));
    c = gf * c + gi * gg;               // redundant x4, deterministic
    float h = go * tanh_fast(c);
    _Float16 hf16 = (_Float16)h;
    uint32 hz = (uint32)__builtin_bit_cast(unsigned short, hf16);
    uint32 hn = (uint32)__shfl_xor((int)hz, 1, 64);   // partner unit u^1
    if (q == 0) {
      ((unsigned short*)&hown[(tt + 1) & 1][0])[u] = (unsigned short)hz;
      ostage[tt & 15][u] = h;
      if (tt < CH - 1 && (l & 1) == 0) {  // post pair (u,u+1), tag = gs+1
        uint64 msg = (uint64)(hz | (hn << 16)) | ((uint64)(gs + 1) << 32);
        __hip_atomic_store(&hx_own[(size_t)((tt + 1) & 1) * 64 + (u >> 1)], msg,
                           __ATOMIC_RELAXED, __HIP_MEMORY_SCOPE_AGENT);
      }
      if (ch == NCH - 1 && tt == CH - 1) {
        float* os = out + (size_t)LSTM_N * LSTM_T * LSTM_H + n * 512;
        os[128 * p + u] = h;
        os[256 + 128 * p + u] = c;
      }
    }
    __syncthreads();                    // BAR-2: hown/ostage visible
    if ((tt & 15) == 15) {              // flush 16 staged steps, coalesced
      int sl = t >> 5, q4 = t & 31;
      float4 v = *(const float4*)&ostage[sl][4 * q4];
      *(float4*)&outb[(size_t)(tt - 15 + sl) * LSTM_H + 128 * p + 4 * q4] = v;
    }
  }
  // persist carried state (CH even -> final h landed in hown[0])
  if (q == 0) cst[n * 256 + 128 * p + u] = c;
  if (t < 64) hst[n * 128 + 64 * p + t] = hown[0][t];
}

extern "C" void kernel_launch(void* const* d_in, const int* in_sizes, int n_in,
                              void* d_out, int out_size, void* d_ws, size_t ws_size,
                              hipStream_t stream) {
  const float* x   = (const float*)d_in[0];
  const float* st  = (const float*)d_in[1];
  const float* wih = (const float*)d_in[2];
  const float* whh = (const float*)d_in[3];
  const float* bih = (const float*)d_in[4];
  const float* bhh = (const float*)d_in[5];
  float* out = (float*)d_out;
  char* ws = (char*)d_ws;

  float* xg = (float*)(ws + OFF_XG);
  unsigned short* wihb = (unsigned short*)(ws + OFF_WIHB);
  float* bias = (float*)(ws + OFF_BIAS);
  uint32* wpk = (uint32*)(ws + OFF_WPK);
  float* cst = (float*)(ws + OFF_CST);
  uint32* hst = (uint32*)(ws + OFF_HST);
  uint64* hx = (uint64*)(ws + OFF_HX);

  cvt_bf16_k<<<(NG * LSTM_D / 4 + 255) / 256, 256, 0, stream>>>(wih, wihb, NG * LSTM_D);
  bias_sum_k<<<4, 256, 0, stream>>>(bih, bhh, bias);
  wpack_k<<<512, 256, 0, stream>>>(whh, wpk);
  state_init_k<<<32, 256, 0, stream>>>(st, cst, hst, hx);

  for (int ch = 0; ch < NCH; ++ch) {
    gemm_xg<<<dim3(NG / 128, MCH / 128), 256, 0, stream>>>(x, wihb, bias, xg, ch);
    lstm_scan<<<64, 512, 0, stream>>>(xg, (const uint4*)wpk, cst, hst, hx, out, ch);
  }
}